// Round 20
// baseline (111.875 us; speedup 1.0000x reference)
//
#include <hip/hip_runtime.h>

typedef __attribute__((ext_vector_type(8))) short short8;
typedef __attribute__((ext_vector_type(4))) float f32x4;
typedef __attribute__((ext_vector_type(4))) short short4v;

template<bool B> struct BoolC { static constexpr bool value = B; };

__device__ __forceinline__ short f2bs(float f) {
    union { float f; unsigned u; } c; c.f = f;
    unsigned r = 0x7FFFu + ((c.u >> 16) & 1u);
    return (short)((c.u + r) >> 16);
}

__device__ __forceinline__ unsigned fbits(float f) {
    union { float f; unsigned u; } c; c.f = f; return c.u;
}

__device__ __forceinline__ float fast_exp2(float x) {
    float r;
    asm("v_exp_f32 %0, %1" : "=v"(r) : "v"(x));
    return r;
}

__device__ __forceinline__ void gld_lds16(const void* g, void* l) {
    __builtin_amdgcn_global_load_lds(
        (const __attribute__((address_space(1))) unsigned int*)g,
        (__attribute__((address_space(3))) unsigned int*)l, 16, 0, 0);
}

__device__ __forceinline__ f32x4 mfma16(short8 a, short8 b, f32x4 c) {
    return __builtin_amdgcn_mfma_f32_16x16x32_bf16(a, b, c, 0, 0, 0);
}

template<int N> __device__ __forceinline__ void vmwait() {
    if constexpr (N == 0)      asm volatile("s_waitcnt vmcnt(0)" ::: "memory");
    else if constexpr (N == 3) asm volatile("s_waitcnt vmcnt(3)" ::: "memory");
    else if constexpr (N == 4) asm volatile("s_waitcnt vmcnt(4)" ::: "memory");
}

// ------------- fused conversion: x, Wq, Wk, Wv, Wo -> bf16 workspaces -------------
__global__ __launch_bounds__(256) void cvtall_kernel(
    const float* __restrict__ x,
    const float* __restrict__ Wq, const float* __restrict__ Wk,
    const float* __restrict__ Wv, const float* __restrict__ Wo,
    short* __restrict__ xb, short* __restrict__ wqkv, short* __restrict__ wob)
{
    int i = blockIdx.x * 256 + threadIdx.x;         // 2M granules of float4
    const float* src; short* dst; int off;
    if (i < 1048576) { src = x; dst = xb; off = i; }
    else {
        int j = i - 1048576, which = j >> 18;
        off = j & 262143;
        src = which == 0 ? Wq : (which == 1 ? Wk : (which == 2 ? Wv : Wo));
        dst = which == 3 ? wob : (wqkv + (size_t)which * 1048576);
    }
    float4 v = ((const float4*)src)[off];
    short4v o;
    o.x = f2bs(v.x); o.y = f2bs(v.y); o.z = f2bs(v.z); o.w = f2bs(v.w);
    ((short4v*)dst)[off] = o;
}

// ---------------- GEMM: C = A @ B^T (B stored [N][K] row-major) ----------------
// 3-buffer LDS pipeline with counted vmcnt (T4). Parameterized geometry:
// MODE 0: 512 thr, BM=128 x BN=256 (8 waves 2x4) — 256 MFMA per 48KB staging/CU.
// MODE 1: 256 thr, BM=64  x BN=128 (4 waves 2x2).
#define BK 32

template<int MODE, int BMt, int BNt, int NTHR>
__global__ __launch_bounds__(NTHR) void gemm_bt(
    const short* __restrict__ A, const short* __restrict__ B,
    int M, int N, int K,
    const float* __restrict__ b0, const float* __restrict__ b1, const float* __restrict__ b2,
    short* __restrict__ oq, short* __restrict__ ok_, short* __restrict__ ov,
    const float* __restrict__ bo, const float* __restrict__ xres,
    float* __restrict__ outf)
{
    constexpr int WCOLS = BNt / 64;                  // wave-cols (4 or 2)
    constexpr int IM = BMt / 2 / 16;                 // 2 wave-rows; acc rows per wave
    constexpr int BUFSZ = (BMt + BNt) * BK;          // shorts per buffer
    __shared__ __align__(16) short SM[3 * BUFSZ];
    const int tid = threadIdx.x;
    const int wave = tid >> 6, lane = tid & 63;
    const int lhi = lane >> 4, llo = lane & 15;
    const int row0 = blockIdx.x * BMt, col0 = blockIdx.y * BNt;
    const int wr = (wave / WCOLS) * (BMt / 2);
    const int wc = (wave % WCOLS) * 64;

    f32x4 acc[IM][4] = {};

    // staging: 1 A-call + 2 B-calls per thread (both modes); linear LDS dest
    const short* gA0 = A + (size_t)(row0 + (tid >> 2)) * K + (tid & 3) * 8;
    const short* gB0 = B + (size_t)(col0 + (tid >> 2)) * K + (tid & 3) * 8;
    const short* gB1 = B + (size_t)(col0 + NTHR / 4 + (tid >> 2)) * K + (tid & 3) * 8;

    auto stage = [&](int kk, int bf) {
        short* As = SM + bf * BUFSZ;
        short* Bs = As + BMt * BK;
        gld_lds16(gA0 + kk, &As[wave * 512]);
        gld_lds16(gB0 + kk, &Bs[wave * 512]);
        gld_lds16(gB1 + kk, &Bs[NTHR * 8 + wave * 512]);
    };

    const int NT = K / BK;
    stage(0, 0);
    stage(BK, 1);

    for (int kt = 0; kt < NT; ++kt) {
        if (kt < NT - 1) vmwait<3>(); else vmwait<0>();
        __builtin_amdgcn_s_barrier();
        __builtin_amdgcn_sched_barrier(0);
        if (kt + 2 < NT) stage((kt + 2) * BK, (kt + 2) % 3);
        const short* As = SM + (kt % 3) * BUFSZ;
        const short* Bs = As + BMt * BK;
        short8 af[IM], bfr[4];
        #pragma unroll
        for (int i = 0; i < IM; ++i)
            af[i] = *(const short8*)&As[(wr + i * 16 + llo) * BK + lhi * 8];
        #pragma unroll
        for (int j = 0; j < 4; ++j)
            bfr[j] = *(const short8*)&Bs[(wc + j * 16 + llo) * BK + lhi * 8];
        #pragma unroll
        for (int i = 0; i < IM; ++i)
            #pragma unroll
            for (int j = 0; j < 4; ++j)
                acc[i][j] = mfma16(af[i], bfr[j], acc[i][j]);
    }

    // epilogue — C/D layout: col = lane&15, row = (lane>>4)*4 + reg
    if constexpr (MODE == 0) {
        const int which = col0 >> 10;              // 256-col blocks divide 1024 exactly
        if (which < 2) {
            const float* bia = which == 0 ? b0 : b1;
            short* dst = which == 0 ? oq : ok_;
            #pragma unroll
            for (int i = 0; i < IM; ++i)
                #pragma unroll
                for (int j = 0; j < 4; ++j)
                    #pragma unroll
                    for (int r = 0; r < 4; ++r) {
                        int m = row0 + wr + i * 16 + lhi * 4 + r;
                        int nn = (col0 & 1023) + wc + j * 16 + llo;
                        float v = acc[i][j][r] + bia[nn];
                        int h = nn >> 6, d = nn & 63;
                        int bb = m >> 11, s = m & 2047;
                        dst[((size_t)((bb * 16 + h) * 2048 + s)) * 64 + d] = f2bs(v);
                    }
        } else {
            // V: transpose per-wave 64x16 tiles through LDS, coalesced short8 stores
            __syncthreads();                           // staging reads all done
            short* T = SM + wave * (64 * 26);
            const int nn0 = (col0 - 2048) + wc;        // multiple of 64 -> one head
            const int h = nn0 >> 6;
            const int bb = row0 >> 11;
            const int s0 = (row0 & 2047) + wr;
            short* vdst = ov + ((size_t)(bb * 16 + h) * 64) * 2048;
            #pragma unroll
            for (int i = 0; i < IM; ++i) {
                #pragma unroll
                for (int j = 0; j < 4; ++j) {
                    const float bias = b2[nn0 + j * 16 + llo];
                    unsigned u01 = __builtin_amdgcn_perm(fbits(acc[i][j][1] + bias),
                                                         fbits(acc[i][j][0] + bias), 0x07060302u);
                    unsigned u23 = __builtin_amdgcn_perm(fbits(acc[i][j][3] + bias),
                                                         fbits(acc[i][j][2] + bias), 0x07060302u);
                    unsigned* Tw = (unsigned*)&T[(j * 16 + llo) * 26];
                    Tw[lhi * 2]     = u01;
                    Tw[lhi * 2 + 1] = u23;
                }
                short8 a0 = *(const short8*)&T[lane * 26];
                short8 a1 = *(const short8*)&T[lane * 26 + 8];
                *(short8*)&vdst[(size_t)lane * 2048 + s0 + i * 16]     = a0;
                *(short8*)&vdst[(size_t)lane * 2048 + s0 + i * 16 + 8] = a1;
            }
        }
    } else {
        #pragma unroll
        for (int i = 0; i < IM; ++i)
            #pragma unroll
            for (int j = 0; j < 4; ++j)
                #pragma unroll
                for (int r = 0; r < 4; ++r) {
                    int m = row0 + wr + i * 16 + lhi * 4 + r;
                    int n = col0 + wc + j * 16 + llo;
                    size_t idx = (size_t)m * N + n;
                    outf[idx] = acc[i][j][r] + bo[n] + xres[idx];
                }
    }
}

// ---------------- flash attention (causal), per (b,h) ----------------
// R17 version: triangle-paired; swapped QK^T; no-max softmax; v_exp_f32; b64 P-writes.
#define SCL 0.18033688011f      /* (1/8) * log2(e) */

__global__ __launch_bounds__(256) void attn_kernel(
    const short* __restrict__ Q, const short* __restrict__ K,
    const short* __restrict__ Vt, short* __restrict__ O)
{
    const int id = blockIdx.x;                        // 512 blocks
    const int u = id >> 3;                            // 0..63
    const int bh = (id & 7) * 4 + (u & 3);            // XCD-grouped bh
    const int s4 = u >> 2;                            // 0..15
    const int p = (s4 < 8) ? (2 * s4) : (31 - 2 * s4);// complementary pairing
    const int q0L = p * 64, q0H = (31 - p) * 64;
    const int ntH = 32 - p;                           // kv tiles for heavy

    const short* Qb = Q  + (size_t)bh * 2048 * 64;
    const short* Kb = K  + (size_t)bh * 2048 * 64;
    const short* Vb = Vt + (size_t)bh * 64 * 2048;

    __shared__ __align__(16) short Ks[2][64 * 64];
    __shared__ __align__(16) short Vs[2][64 * 64];
    __shared__ __align__(16) short Ps[4][2][16 * 68]; // [wave][H/L][..] stride-68

    const int tid = threadIdx.x, wave = tid >> 6, lane = tid & 63;
    const int lhi = lane >> 4, llo = lane & 15;
    const int qwL = q0L + wave * 16, qwH = q0H + wave * 16;
    const int qgL = qwL + llo, qgH = qwH + llo;

    // Q fragments, pre-scaled by SCL (folds softmax scale into the MFMA)
    auto scale8 = [](short8 a) {
        short8 r;
        #pragma unroll
        for (int i = 0; i < 8; ++i) {
            union { unsigned u; float f; } c; c.u = ((unsigned)(unsigned short)a[i]) << 16;
            r[i] = f2bs(c.f * SCL);
        }
        return r;
    };
    const short8 qfL0 = scale8(*(const short8*)&Qb[(size_t)(qwL + llo) * 64 + lhi * 8]);
    const short8 qfL1 = scale8(*(const short8*)&Qb[(size_t)(qwL + llo) * 64 + 32 + lhi * 8]);
    const short8 qfH0 = scale8(*(const short8*)&Qb[(size_t)(qwH + llo) * 64 + lhi * 8]);
    const short8 qfH1 = scale8(*(const short8*)&Qb[(size_t)(qwH + llo) * 64 + 32 + lhi * 8]);

    // staging: linear LDS dest, pre-XOR-swizzled global source (involution)
    const int tr = tid >> 3, tc = tid & 7, sc = tc ^ (tr & 7);
    const short* kS0 = Kb + (size_t)tr * 64 + sc * 8;
    const short* kS1 = Kb + (size_t)(32 + tr) * 64 + sc * 8;
    const short* vS0 = Vb + (size_t)tr * 2048 + sc * 8;
    const short* vS1 = Vb + (size_t)(32 + tr) * 2048 + sc * 8;
    const int dOff = wave * 512;

    f32x4 oL[4] = {}, oH[4] = {};
    float lL = 0.f, lH = 0.f;                         // per-lane partial row sums

    unsigned* PwH = (unsigned*)Ps[wave][0] + llo * 34;
    unsigned* PwL = (unsigned*)Ps[wave][1] + llo * 34;

    gld_lds16(kS0, Ks[0] + dOff);
    gld_lds16(kS1, Ks[0] + 2048 + dOff);
    gld_lds16(vS0, Vs[0] + dOff);
    gld_lds16(vS1, Vs[0] + 2048 + dOff);
    __syncthreads();

    const int swq = (llo & 7) << 3;                   // K/V row-XOR

    // no-max softmax: v_exp_f32 + per-lane partial sum + b64 perm-pack writes.
    auto smx = [&](f32x4 (&st)[4], float& lrow, unsigned* Pw, int qg, int kk0, bool diag) {
        if (diag) {
            #pragma unroll
            for (int t = 0; t < 4; ++t)
                #pragma unroll
                for (int j = 0; j < 4; ++j)
                    if (kk0 + t * 16 + lhi * 4 + j > qg) st[t][j] = -1e30f;
        }
        float rs0 = 0.f, rs1 = 0.f;
        #pragma unroll
        for (int t = 0; t < 4; ++t) {
            st[t][0] = fast_exp2(st[t][0]);
            st[t][1] = fast_exp2(st[t][1]);
            st[t][2] = fast_exp2(st[t][2]);
            st[t][3] = fast_exp2(st[t][3]);
            rs0 += st[t][0] + st[t][2];
            rs1 += st[t][1] + st[t][3];
        }
        lrow += rs0 + rs1;
        #pragma unroll
        for (int t = 0; t < 4; ++t) {
            uint2 w;
            w.x = __builtin_amdgcn_perm(fbits(st[t][1]), fbits(st[t][0]), 0x07060302u);
            w.y = __builtin_amdgcn_perm(fbits(st[t][3]), fbits(st[t][2]), 0x07060302u);
            *(uint2*)&Pw[t * 8 + lhi * 2] = w;
        }
    };

    int cur = 0;
    auto tile = [&](int kt, auto dualc) {
        constexpr bool DUAL = decltype(dualc)::value;
        const int kk0 = kt * 64;
        if (kt + 1 < ntH) {
            const int nk = kk0 + 64;
            gld_lds16(kS0 + (size_t)nk * 64, Ks[cur ^ 1] + dOff);
            gld_lds16(kS1 + (size_t)nk * 64, Ks[cur ^ 1] + 2048 + dOff);
            gld_lds16(vS0 + nk, Vs[cur ^ 1] + dOff);
            gld_lds16(vS1 + nk, Vs[cur ^ 1] + 2048 + dOff);
        }

        // ---- S^T = K Q^T, shared K fragments ----
        f32x4 stH[4], stL[4];
        __builtin_amdgcn_s_setprio(1);
        #pragma unroll
        for (int t = 0; t < 4; ++t) {
            const int row = t * 16 + llo;
            short8 kf0 = *(const short8*)&Ks[cur][row * 64 + ((lhi * 8) ^ swq)];
            short8 kf1 = *(const short8*)&Ks[cur][row * 64 + ((lhi * 8 + 32) ^ swq)];
            f32x4 a = {};
            a = mfma16(kf0, qfH0, a);
            stH[t] = mfma16(kf1, qfH1, a);
            if (DUAL) {
                f32x4 b = {};
                b = mfma16(kf0, qfL0, b);
                stL[t] = mfma16(kf1, qfL1, b);
            }
        }
        __builtin_amdgcn_s_setprio(0);

        smx(stH, lH, PwH, qgH, kk0, kt == ntH - 1);
        if (DUAL) smx(stL, lL, PwL, qgL, kk0, kt == p);

        // ---- O += P V, shared V fragments ----
        const short8 pH0 = *(const short8*)&Ps[wave][0][llo * 68 + lhi * 8];
        const short8 pH1 = *(const short8*)&Ps[wave][0][llo * 68 + 32 + lhi * 8];
        short8 pL0, pL1;
        if (DUAL) {
            pL0 = *(const short8*)&Ps[wave][1][llo * 68 + lhi * 8];
            pL1 = *(const short8*)&Ps[wave][1][llo * 68 + 32 + lhi * 8];
        }
        __builtin_amdgcn_s_setprio(1);
        #pragma unroll
        for (int dt = 0; dt < 4; ++dt) {
            const int row = dt * 16 + llo;
            short8 vf0 = *(const short8*)&Vs[cur][row * 64 + ((lhi * 8) ^ swq)];
            short8 vf1 = *(const short8*)&Vs[cur][row * 64 + ((lhi * 8 + 32) ^ swq)];
            oH[dt] = mfma16(pH0, vf0, oH[dt]);
            oH[dt] = mfma16(pH1, vf1, oH[dt]);
            if (DUAL) {
                oL[dt] = mfma16(pL0, vf0, oL[dt]);
                oL[dt] = mfma16(pL1, vf1, oL[dt]);
            }
        }
        __builtin_amdgcn_s_setprio(0);

        if (kt + 1 < ntH) __syncthreads();
        cur ^= 1;
    };

    for (int kt = 0; kt <= p; ++kt)      tile(kt, BoolC<true>{});
    for (int kt = p + 1; kt < ntH; ++kt) tile(kt, BoolC<false>{});

    // finalize: reduce l once, write [4096][1024] (col = h*64+d)
    lH += __shfl_xor(lH, 16); lH += __shfl_xor(lH, 32);
    lL += __shfl_xor(lL, 16); lL += __shfl_xor(lL, 32);
    const int b = bh >> 4, h = bh & 15;
    const float invH = 1.f / lH, invL = 1.f / lL;
    #pragma unroll
    for (int j = 0; j < 4; ++j) {
        const float ivH = __shfl(invH, lhi * 4 + j);
        const float ivL = __shfl(invL, lhi * 4 + j);
        const size_t rowH = (size_t)(b * 2048 + qwH + lhi * 4 + j);
        const size_t rowL = (size_t)(b * 2048 + qwL + lhi * 4 + j);
        #pragma unroll
        for (int dt = 0; dt < 4; ++dt) {
            int d = dt * 16 + llo;
            O[rowH * 1024 + h * 64 + d] = f2bs(oH[dt][j] * ivH);
            O[rowL * 1024 + h * 64 + d] = f2bs(oL[dt][j] * ivL);
        }
    }
}

// ---------------- in-place LayerNorm over rows of 1024 ----------------
__global__ __launch_bounds__(256) void ln_kernel(float* __restrict__ out,
        const float* __restrict__ gamma, const float* __restrict__ beta)
{
    const int row = blockIdx.x;
    float* p = out + (size_t)row * 1024;
    const int tid = threadIdx.x;
    float4 v = ((const float4*)p)[tid];
    float s = v.x + v.y + v.z + v.w;
    float ss = v.x * v.x + v.y * v.y + v.z * v.z + v.w * v.w;
    #pragma unroll
    for (int d = 1; d < 64; d <<= 1) {
        s  += __shfl_xor(s, d);
        ss += __shfl_xor(ss, d);
    }
    __shared__ float red[8];
    const int wave = tid >> 6, lane = tid & 63;
    if (lane == 0) { red[wave] = s; red[4 + wave] = ss; }
    __syncthreads();
    s  = red[0] + red[1] + red[2] + red[3];
    ss = red[4] + red[5] + red[6] + red[7];
    const float mu = s * (1.0f / 1024.0f);
    const float var = ss * (1.0f / 1024.0f) - mu * mu;
    const float rstd = rsqrtf(var + 1e-5f);
    float4 g = ((const float4*)gamma)[tid];
    float4 b = ((const float4*)beta)[tid];
    v.x = (v.x - mu) * rstd * g.x + b.x;
    v.y = (v.y - mu) * rstd * g.y + b.y;
    v.z = (v.z - mu) * rstd * g.z + b.z;
    v.w = (v.w - mu) * rstd * g.w + b.w;
    ((float4*)p)[tid] = v;
}

extern "C" void kernel_launch(void* const* d_in, const int* in_sizes, int n_in,
                              void* d_out, int out_size, void* d_ws, size_t ws_size,
                              hipStream_t stream)
{
    const float* x  = (const float*)d_in[0];
    const float* Wq = (const float*)d_in[1];
    const float* bq = (const float*)d_in[2];
    const float* Wk = (const float*)d_in[3];
    const float* bk = (const float*)d_in[4];
    const float* Wv = (const float*)d_in[5];
    const float* bv = (const float*)d_in[6];
    const float* Wo = (const float*)d_in[7];
    const float* bo = (const float*)d_in[8];
    const float* gamma = (const float*)d_in[9];
    const float* beta  = (const float*)d_in[10];
    float* out = (float*)d_out;

    char* ws = (char*)d_ws;
    short* xb   = (short*)(ws);                      // 8 MB; reused as ab
    short* wqkv = (short*)(ws + (8ull  << 20));      // 6 MB [3072][1024]
    short* wob  = (short*)(ws + (14ull << 20));      // 2 MB
    short* qb   = (short*)(ws + (16ull << 20));      // [2][16][2048][64] bf16
    short* kb   = (short*)(ws + (24ull << 20));      // [2][16][2048][64]
    short* vtb  = (short*)(ws + (32ull << 20));      // [2][16][64][2048]  (transposed)
    short* ab   = xb;                                // attn out [4096][1024]

    cvtall_kernel<<<8192, 256, 0, stream>>>(x, Wq, Wk, Wv, Wo, xb, wqkv, wob);

    gemm_bt<0, 128, 256, 512><<<dim3(32, 12), 512, 0, stream>>>(xb, wqkv, 4096, 3072, 1024,
        bq, bk, bv, qb, kb, vtb, nullptr, nullptr, nullptr);

    attn_kernel<<<512, 256, 0, stream>>>(qb, kb, vtb, ab);

    gemm_bt<1, 64, 128, 256><<<dim3(64, 8), 256, 0, stream>>>(ab, wob, 4096, 1024, 1024,
        nullptr, nullptr, nullptr, nullptr, nullptr, nullptr, bo, x, out);

    ln_kernel<<<4096, 256, 0, stream>>>(out, gamma, beta);
}

// Round 21
// 107.248 us; speedup vs baseline: 1.0431x; 1.0431x over previous
//
#include <hip/hip_runtime.h>

typedef __attribute__((ext_vector_type(8))) short short8;
typedef __attribute__((ext_vector_type(4))) float f32x4;
typedef __attribute__((ext_vector_type(4))) short short4v;

template<bool B> struct BoolC { static constexpr bool value = B; };

__device__ __forceinline__ short f2bs(float f) {
    union { float f; unsigned u; } c; c.f = f;
    unsigned r = 0x7FFFu + ((c.u >> 16) & 1u);
    return (short)((c.u + r) >> 16);
}

__device__ __forceinline__ float bs2f(short s) {
    union { unsigned u; float f; } c; c.u = ((unsigned)(unsigned short)s) << 16;
    return c.f;
}

__device__ __forceinline__ unsigned fbits(float f) {
    union { float f; unsigned u; } c; c.f = f; return c.u;
}

__device__ __forceinline__ float fast_exp2(float x) {
    float r;
    asm("v_exp_f32 %0, %1" : "=v"(r) : "v"(x));
    return r;
}

__device__ __forceinline__ void gld_lds16(const void* g, void* l) {
    __builtin_amdgcn_global_load_lds(
        (const __attribute__((address_space(1))) unsigned int*)g,
        (__attribute__((address_space(3))) unsigned int*)l, 16, 0, 0);
}

__device__ __forceinline__ f32x4 mfma16(short8 a, short8 b, f32x4 c) {
    return __builtin_amdgcn_mfma_f32_16x16x32_bf16(a, b, c, 0, 0, 0);
}

template<int N> __device__ __forceinline__ void vmwait() {
    if constexpr (N == 0)      asm volatile("s_waitcnt vmcnt(0)" ::: "memory");
    else if constexpr (N == 3) asm volatile("s_waitcnt vmcnt(3)" ::: "memory");
    else if constexpr (N == 4) asm volatile("s_waitcnt vmcnt(4)" ::: "memory");
}

// ------------- fused conversion: x, Wq, Wk, Wv, Wo -> bf16 workspaces -------------
__global__ __launch_bounds__(256) void cvtall_kernel(
    const float* __restrict__ x,
    const float* __restrict__ Wq, const float* __restrict__ Wk,
    const float* __restrict__ Wv, const float* __restrict__ Wo,
    short* __restrict__ xb, short* __restrict__ wqkv, short* __restrict__ wob)
{
    int i = blockIdx.x * 256 + threadIdx.x;         // 2M granules of float4
    const float* src; short* dst; int off;
    if (i < 1048576) { src = x; dst = xb; off = i; }
    else {
        int j = i - 1048576, which = j >> 18;
        off = j & 262143;
        src = which == 0 ? Wq : (which == 1 ? Wk : (which == 2 ? Wv : Wo));
        dst = which == 3 ? wob : (wqkv + (size_t)which * 1048576);
    }
    float4 v = ((const float4*)src)[off];
    short4v o;
    o.x = f2bs(v.x); o.y = f2bs(v.y); o.z = f2bs(v.z); o.w = f2bs(v.w);
    ((short4v*)dst)[off] = o;
}

// ---------------- GEMM: C = A @ B^T (B stored [N][K] row-major) ----------------
// 3-buffer LDS pipeline with counted vmcnt (T4). Parameterized geometry:
// MODE 0: 512 thr, BM=128 x BN=256 (8 waves 2x4) — 256 MFMA per 48KB staging/CU.
// MODE 1: 256 thr, BM=64  x BN=128 (4 waves 2x2) — + bo + residual x, write BF16 h.
#define BK 32

template<int MODE, int BMt, int BNt, int NTHR>
__global__ __launch_bounds__(NTHR) void gemm_bt(
    const short* __restrict__ A, const short* __restrict__ B,
    int M, int N, int K,
    const float* __restrict__ b0, const float* __restrict__ b1, const float* __restrict__ b2,
    short* __restrict__ oq, short* __restrict__ ok_, short* __restrict__ ov,
    const float* __restrict__ bo, const float* __restrict__ xres,
    short* __restrict__ outh)
{
    constexpr int WCOLS = BNt / 64;                  // wave-cols (4 or 2)
    constexpr int IM = BMt / 2 / 16;                 // 2 wave-rows; acc rows per wave
    constexpr int BUFSZ = (BMt + BNt) * BK;          // shorts per buffer
    __shared__ __align__(16) short SM[3 * BUFSZ];
    const int tid = threadIdx.x;
    const int wave = tid >> 6, lane = tid & 63;
    const int lhi = lane >> 4, llo = lane & 15;
    const int row0 = blockIdx.x * BMt, col0 = blockIdx.y * BNt;
    const int wr = (wave / WCOLS) * (BMt / 2);
    const int wc = (wave % WCOLS) * 64;

    f32x4 acc[IM][4] = {};

    // staging: 1 A-call + 2 B-calls per thread (both modes); linear LDS dest
    const short* gA0 = A + (size_t)(row0 + (tid >> 2)) * K + (tid & 3) * 8;
    const short* gB0 = B + (size_t)(col0 + (tid >> 2)) * K + (tid & 3) * 8;
    const short* gB1 = B + (size_t)(col0 + NTHR / 4 + (tid >> 2)) * K + (tid & 3) * 8;

    auto stage = [&](int kk, int bf) {
        short* As = SM + bf * BUFSZ;
        short* Bs = As + BMt * BK;
        gld_lds16(gA0 + kk, &As[wave * 512]);
        gld_lds16(gB0 + kk, &Bs[wave * 512]);
        gld_lds16(gB1 + kk, &Bs[NTHR * 8 + wave * 512]);
    };

    const int NT = K / BK;
    stage(0, 0);
    stage(BK, 1);

    for (int kt = 0; kt < NT; ++kt) {
        if (kt < NT - 1) vmwait<3>(); else vmwait<0>();
        __builtin_amdgcn_s_barrier();
        __builtin_amdgcn_sched_barrier(0);
        if (kt + 2 < NT) stage((kt + 2) * BK, (kt + 2) % 3);
        const short* As = SM + (kt % 3) * BUFSZ;
        const short* Bs = As + BMt * BK;
        short8 af[IM], bfr[4];
        #pragma unroll
        for (int i = 0; i < IM; ++i)
            af[i] = *(const short8*)&As[(wr + i * 16 + llo) * BK + lhi * 8];
        #pragma unroll
        for (int j = 0; j < 4; ++j)
            bfr[j] = *(const short8*)&Bs[(wc + j * 16 + llo) * BK + lhi * 8];
        #pragma unroll
        for (int i = 0; i < IM; ++i)
            #pragma unroll
            for (int j = 0; j < 4; ++j)
                acc[i][j] = mfma16(af[i], bfr[j], acc[i][j]);
    }

    // epilogue — C/D layout: col = lane&15, row = (lane>>4)*4 + reg
    if constexpr (MODE == 0) {
        const int which = col0 >> 10;              // 256-col blocks divide 1024 exactly
        if (which < 2) {
            const float* bia = which == 0 ? b0 : b1;
            short* dst = which == 0 ? oq : ok_;
            #pragma unroll
            for (int i = 0; i < IM; ++i)
                #pragma unroll
                for (int j = 0; j < 4; ++j)
                    #pragma unroll
                    for (int r = 0; r < 4; ++r) {
                        int m = row0 + wr + i * 16 + lhi * 4 + r;
                        int nn = (col0 & 1023) + wc + j * 16 + llo;
                        float v = acc[i][j][r] + bia[nn];
                        int h = nn >> 6, d = nn & 63;
                        int bb = m >> 11, s = m & 2047;
                        dst[((size_t)((bb * 16 + h) * 2048 + s)) * 64 + d] = f2bs(v);
                    }
        } else {
            // V: transpose per-wave 64x16 tiles through LDS, coalesced short8 stores
            __syncthreads();                           // staging reads all done
            short* T = SM + wave * (64 * 26);
            const int nn0 = (col0 - 2048) + wc;        // multiple of 64 -> one head
            const int h = nn0 >> 6;
            const int bb = row0 >> 11;
            const int s0 = (row0 & 2047) + wr;
            short* vdst = ov + ((size_t)(bb * 16 + h) * 64) * 2048;
            #pragma unroll
            for (int i = 0; i < IM; ++i) {
                #pragma unroll
                for (int j = 0; j < 4; ++j) {
                    const float bias = b2[nn0 + j * 16 + llo];
                    unsigned u01 = __builtin_amdgcn_perm(fbits(acc[i][j][1] + bias),
                                                         fbits(acc[i][j][0] + bias), 0x07060302u);
                    unsigned u23 = __builtin_amdgcn_perm(fbits(acc[i][j][3] + bias),
                                                         fbits(acc[i][j][2] + bias), 0x07060302u);
                    unsigned* Tw = (unsigned*)&T[(j * 16 + llo) * 26];
                    Tw[lhi * 2]     = u01;
                    Tw[lhi * 2 + 1] = u23;
                }
                short8 a0 = *(const short8*)&T[lane * 26];
                short8 a1 = *(const short8*)&T[lane * 26 + 8];
                *(short8*)&vdst[(size_t)lane * 2048 + s0 + i * 16]     = a0;
                *(short8*)&vdst[(size_t)lane * 2048 + s0 + i * 16 + 8] = a1;
            }
        }
    } else {
        // h = acc + bo + x  -> bf16 workspace (LN reads it)
        #pragma unroll
        for (int i = 0; i < IM; ++i)
            #pragma unroll
            for (int j = 0; j < 4; ++j)
                #pragma unroll
                for (int r = 0; r < 4; ++r) {
                    int m = row0 + wr + i * 16 + lhi * 4 + r;
                    int n = col0 + wc + j * 16 + llo;
                    size_t idx = (size_t)m * N + n;
                    outh[idx] = f2bs(acc[i][j][r] + bo[n] + xres[idx]);
                }
    }
}

// ---------------- flash attention (causal), per (b,h) ----------------
// R17 version: triangle-paired; swapped QK^T; no-max softmax; v_exp_f32; b64 P-writes.
#define SCL 0.18033688011f      /* (1/8) * log2(e) */

__global__ __launch_bounds__(256) void attn_kernel(
    const short* __restrict__ Q, const short* __restrict__ K,
    const short* __restrict__ Vt, short* __restrict__ O)
{
    const int id = blockIdx.x;                        // 512 blocks
    const int u = id >> 3;                            // 0..63
    const int bh = (id & 7) * 4 + (u & 3);            // XCD-grouped bh
    const int s4 = u >> 2;                            // 0..15
    const int p = (s4 < 8) ? (2 * s4) : (31 - 2 * s4);// complementary pairing
    const int q0L = p * 64, q0H = (31 - p) * 64;
    const int ntH = 32 - p;                           // kv tiles for heavy

    const short* Qb = Q  + (size_t)bh * 2048 * 64;
    const short* Kb = K  + (size_t)bh * 2048 * 64;
    const short* Vb = Vt + (size_t)bh * 64 * 2048;

    __shared__ __align__(16) short Ks[2][64 * 64];
    __shared__ __align__(16) short Vs[2][64 * 64];
    __shared__ __align__(16) short Ps[4][2][16 * 68]; // [wave][H/L][..] stride-68

    const int tid = threadIdx.x, wave = tid >> 6, lane = tid & 63;
    const int lhi = lane >> 4, llo = lane & 15;
    const int qwL = q0L + wave * 16, qwH = q0H + wave * 16;
    const int qgL = qwL + llo, qgH = qwH + llo;

    // Q fragments, pre-scaled by SCL (folds softmax scale into the MFMA)
    auto scale8 = [](short8 a) {
        short8 r;
        #pragma unroll
        for (int i = 0; i < 8; ++i) {
            union { unsigned u; float f; } c; c.u = ((unsigned)(unsigned short)a[i]) << 16;
            r[i] = f2bs(c.f * SCL);
        }
        return r;
    };
    const short8 qfL0 = scale8(*(const short8*)&Qb[(size_t)(qwL + llo) * 64 + lhi * 8]);
    const short8 qfL1 = scale8(*(const short8*)&Qb[(size_t)(qwL + llo) * 64 + 32 + lhi * 8]);
    const short8 qfH0 = scale8(*(const short8*)&Qb[(size_t)(qwH + llo) * 64 + lhi * 8]);
    const short8 qfH1 = scale8(*(const short8*)&Qb[(size_t)(qwH + llo) * 64 + 32 + lhi * 8]);

    // staging: linear LDS dest, pre-XOR-swizzled global source (involution)
    const int tr = tid >> 3, tc = tid & 7, sc = tc ^ (tr & 7);
    const short* kS0 = Kb + (size_t)tr * 64 + sc * 8;
    const short* kS1 = Kb + (size_t)(32 + tr) * 64 + sc * 8;
    const short* vS0 = Vb + (size_t)tr * 2048 + sc * 8;
    const short* vS1 = Vb + (size_t)(32 + tr) * 2048 + sc * 8;
    const int dOff = wave * 512;

    f32x4 oL[4] = {}, oH[4] = {};
    float lL = 0.f, lH = 0.f;                         // per-lane partial row sums

    unsigned* PwH = (unsigned*)Ps[wave][0] + llo * 34;
    unsigned* PwL = (unsigned*)Ps[wave][1] + llo * 34;

    gld_lds16(kS0, Ks[0] + dOff);
    gld_lds16(kS1, Ks[0] + 2048 + dOff);
    gld_lds16(vS0, Vs[0] + dOff);
    gld_lds16(vS1, Vs[0] + 2048 + dOff);
    __syncthreads();

    const int swq = (llo & 7) << 3;                   // K/V row-XOR

    // no-max softmax: v_exp_f32 + per-lane partial sum + b64 perm-pack writes.
    auto smx = [&](f32x4 (&st)[4], float& lrow, unsigned* Pw, int qg, int kk0, bool diag) {
        if (diag) {
            #pragma unroll
            for (int t = 0; t < 4; ++t)
                #pragma unroll
                for (int j = 0; j < 4; ++j)
                    if (kk0 + t * 16 + lhi * 4 + j > qg) st[t][j] = -1e30f;
        }
        float rs0 = 0.f, rs1 = 0.f;
        #pragma unroll
        for (int t = 0; t < 4; ++t) {
            st[t][0] = fast_exp2(st[t][0]);
            st[t][1] = fast_exp2(st[t][1]);
            st[t][2] = fast_exp2(st[t][2]);
            st[t][3] = fast_exp2(st[t][3]);
            rs0 += st[t][0] + st[t][2];
            rs1 += st[t][1] + st[t][3];
        }
        lrow += rs0 + rs1;
        #pragma unroll
        for (int t = 0; t < 4; ++t) {
            uint2 w;
            w.x = __builtin_amdgcn_perm(fbits(st[t][1]), fbits(st[t][0]), 0x07060302u);
            w.y = __builtin_amdgcn_perm(fbits(st[t][3]), fbits(st[t][2]), 0x07060302u);
            *(uint2*)&Pw[t * 8 + lhi * 2] = w;
        }
    };

    int cur = 0;
    auto tile = [&](int kt, auto dualc) {
        constexpr bool DUAL = decltype(dualc)::value;
        const int kk0 = kt * 64;
        if (kt + 1 < ntH) {
            const int nk = kk0 + 64;
            gld_lds16(kS0 + (size_t)nk * 64, Ks[cur ^ 1] + dOff);
            gld_lds16(kS1 + (size_t)nk * 64, Ks[cur ^ 1] + 2048 + dOff);
            gld_lds16(vS0 + nk, Vs[cur ^ 1] + dOff);
            gld_lds16(vS1 + nk, Vs[cur ^ 1] + 2048 + dOff);
        }

        // ---- S^T = K Q^T, shared K fragments ----
        f32x4 stH[4], stL[4];
        __builtin_amdgcn_s_setprio(1);
        #pragma unroll
        for (int t = 0; t < 4; ++t) {
            const int row = t * 16 + llo;
            short8 kf0 = *(const short8*)&Ks[cur][row * 64 + ((lhi * 8) ^ swq)];
            short8 kf1 = *(const short8*)&Ks[cur][row * 64 + ((lhi * 8 + 32) ^ swq)];
            f32x4 a = {};
            a = mfma16(kf0, qfH0, a);
            stH[t] = mfma16(kf1, qfH1, a);
            if (DUAL) {
                f32x4 b = {};
                b = mfma16(kf0, qfL0, b);
                stL[t] = mfma16(kf1, qfL1, b);
            }
        }
        __builtin_amdgcn_s_setprio(0);

        smx(stH, lH, PwH, qgH, kk0, kt == ntH - 1);
        if (DUAL) smx(stL, lL, PwL, qgL, kk0, kt == p);

        // ---- O += P V, shared V fragments ----
        const short8 pH0 = *(const short8*)&Ps[wave][0][llo * 68 + lhi * 8];
        const short8 pH1 = *(const short8*)&Ps[wave][0][llo * 68 + 32 + lhi * 8];
        short8 pL0, pL1;
        if (DUAL) {
            pL0 = *(const short8*)&Ps[wave][1][llo * 68 + lhi * 8];
            pL1 = *(const short8*)&Ps[wave][1][llo * 68 + 32 + lhi * 8];
        }
        __builtin_amdgcn_s_setprio(1);
        #pragma unroll
        for (int dt = 0; dt < 4; ++dt) {
            const int row = dt * 16 + llo;
            short8 vf0 = *(const short8*)&Vs[cur][row * 64 + ((lhi * 8) ^ swq)];
            short8 vf1 = *(const short8*)&Vs[cur][row * 64 + ((lhi * 8 + 32) ^ swq)];
            oH[dt] = mfma16(pH0, vf0, oH[dt]);
            oH[dt] = mfma16(pH1, vf1, oH[dt]);
            if (DUAL) {
                oL[dt] = mfma16(pL0, vf0, oL[dt]);
                oL[dt] = mfma16(pL1, vf1, oL[dt]);
            }
        }
        __builtin_amdgcn_s_setprio(0);

        if (kt + 1 < ntH) __syncthreads();
        cur ^= 1;
    };

    for (int kt = 0; kt <= p; ++kt)      tile(kt, BoolC<true>{});
    for (int kt = p + 1; kt < ntH; ++kt) tile(kt, BoolC<false>{});

    // finalize: reduce l once, write [4096][1024] (col = h*64+d)
    lH += __shfl_xor(lH, 16); lH += __shfl_xor(lH, 32);
    lL += __shfl_xor(lL, 16); lL += __shfl_xor(lL, 32);
    const int b = bh >> 4, h = bh & 15;
    const float invH = 1.f / lH, invL = 1.f / lL;
    #pragma unroll
    for (int j = 0; j < 4; ++j) {
        const float ivH = __shfl(invH, lhi * 4 + j);
        const float ivL = __shfl(invL, lhi * 4 + j);
        const size_t rowH = (size_t)(b * 2048 + qwH + lhi * 4 + j);
        const size_t rowL = (size_t)(b * 2048 + qwL + lhi * 4 + j);
        #pragma unroll
        for (int dt = 0; dt < 4; ++dt) {
            int d = dt * 16 + llo;
            O[rowH * 1024 + h * 64 + d] = f2bs(oH[dt][j] * ivH);
            O[rowL * 1024 + h * 64 + d] = f2bs(oL[dt][j] * ivL);
        }
    }
}

// -------- LayerNorm: read bf16 h, write fp32 out (rows of 1024) --------
__global__ __launch_bounds__(256) void ln_kernel(const short* __restrict__ hb,
        float* __restrict__ out,
        const float* __restrict__ gamma, const float* __restrict__ beta)
{
    const int row = blockIdx.x;
    const short* pin = hb + (size_t)row * 1024;
    float* pout = out + (size_t)row * 1024;
    const int tid = threadIdx.x;
    short4v hv = ((const short4v*)pin)[tid];
    float4 v;
    v.x = bs2f(hv.x); v.y = bs2f(hv.y); v.z = bs2f(hv.z); v.w = bs2f(hv.w);
    float s = v.x + v.y + v.z + v.w;
    float ss = v.x * v.x + v.y * v.y + v.z * v.z + v.w * v.w;
    #pragma unroll
    for (int d = 1; d < 64; d <<= 1) {
        s  += __shfl_xor(s, d);
        ss += __shfl_xor(ss, d);
    }
    __shared__ float red[8];
    const int wave = tid >> 6, lane = tid & 63;
    if (lane == 0) { red[wave] = s; red[4 + wave] = ss; }
    __syncthreads();
    s  = red[0] + red[1] + red[2] + red[3];
    ss = red[4] + red[5] + red[6] + red[7];
    const float mu = s * (1.0f / 1024.0f);
    const float var = ss * (1.0f / 1024.0f) - mu * mu;
    const float rstd = rsqrtf(var + 1e-5f);
    float4 g = ((const float4*)gamma)[tid];
    float4 b = ((const float4*)beta)[tid];
    v.x = (v.x - mu) * rstd * g.x + b.x;
    v.y = (v.y - mu) * rstd * g.y + b.y;
    v.z = (v.z - mu) * rstd * g.z + b.z;
    v.w = (v.w - mu) * rstd * g.w + b.w;
    ((float4*)pout)[tid] = v;
}

extern "C" void kernel_launch(void* const* d_in, const int* in_sizes, int n_in,
                              void* d_out, int out_size, void* d_ws, size_t ws_size,
                              hipStream_t stream)
{
    const float* x  = (const float*)d_in[0];
    const float* Wq = (const float*)d_in[1];
    const float* bq = (const float*)d_in[2];
    const float* Wk = (const float*)d_in[3];
    const float* bk = (const float*)d_in[4];
    const float* Wv = (const float*)d_in[5];
    const float* bv = (const float*)d_in[6];
    const float* Wo = (const float*)d_in[7];
    const float* bo = (const float*)d_in[8];
    const float* gamma = (const float*)d_in[9];
    const float* beta  = (const float*)d_in[10];
    float* out = (float*)d_out;

    char* ws = (char*)d_ws;
    short* xb   = (short*)(ws);                      // 8 MB; reused as ab
    short* wqkv = (short*)(ws + (8ull  << 20));      // 6 MB [3072][1024]
    short* wob  = (short*)(ws + (14ull << 20));      // 2 MB
    short* qb   = (short*)(ws + (16ull << 20));      // [2][16][2048][64] bf16
    short* kb   = (short*)(ws + (24ull << 20));      // [2][16][2048][64]
    short* vtb  = (short*)(ws + (32ull << 20));      // [2][16][64][2048]  (transposed)
    short* ab   = xb;                                // attn out [4096][1024]
    short* hb   = qb;                                // bf16 h (qb dead after attn)

    cvtall_kernel<<<8192, 256, 0, stream>>>(x, Wq, Wk, Wv, Wo, xb, wqkv, wob);

    gemm_bt<0, 128, 256, 512><<<dim3(32, 12), 512, 0, stream>>>(xb, wqkv, 4096, 3072, 1024,
        bq, bk, bv, qb, kb, vtb, nullptr, nullptr, nullptr);

    attn_kernel<<<512, 256, 0, stream>>>(qb, kb, vtb, ab);

    gemm_bt<1, 64, 128, 256><<<dim3(64, 8), 256, 0, stream>>>(ab, wob, 4096, 1024, 1024,
        nullptr, nullptr, nullptr, nullptr, nullptr, nullptr, bo, x, hb);

    ln_kernel<<<4096, 256, 0, stream>>>(hb, out, gamma, beta);
}